// Round 1
// baseline (606.322 us; speedup 1.0000x reference)
//
#include <hip/hip_runtime.h>
#include <cfloat>
#include <climits>
#include <cstdint>

#define ALPHA 30.0f
#define KSEL 16          // reference K: threshold = sorted[:,K] (0-based) => 17th smallest
#define BIGV 1e30f

// ---------------------------------------------------------------------------
// Kernel 1: per-row squared norms
// ---------------------------------------------------------------------------
__global__ __launch_bounds__(256) void sqnorm_kernel(const float* __restrict__ X,
                                                     float* __restrict__ sq, int D) {
    int row = blockIdx.x;
    const float4* xr = reinterpret_cast<const float4*>(X + (size_t)row * D);
    float s = 0.f;
    for (int c = threadIdx.x; c < D / 4; c += blockDim.x) {
        float4 v = xr[c];
        s += v.x * v.x + v.y * v.y + v.z * v.z + v.w * v.w;
    }
    // block reduce
    __shared__ float sw[4];
    for (int off = 32; off; off >>= 1) s += __shfl_down(s, off);
    int tid = threadIdx.x, wid = tid >> 6;
    if ((tid & 63) == 0) sw[wid] = s;
    __syncthreads();
    if (tid == 0) sq[row] = sw[0] + sw[1] + sw[2] + sw[3];
}

// ---------------------------------------------------------------------------
// Kernel 2: tiled fp32 "GEMM" -> dist[i][j] = sqrt(max(sq_i + sq_j - 2*dot, 1e-12))
// 128x128 tile, BK=8, 256 threads, 8x8 per thread.
// ---------------------------------------------------------------------------
#define BM 128
#define BN 128
#define BKK 8
__global__ __launch_bounds__(256) void distgemm_kernel(const float* __restrict__ X,
                                                       const float* __restrict__ sq,
                                                       float* __restrict__ dist,
                                                       int N, int D) {
    __shared__ float As[BKK][BM];
    __shared__ float Bs[BKK][BN];
    int tid = threadIdx.x;
    int rowBase = blockIdx.y * BM;
    int colBase = blockIdx.x * BN;

    int lrow  = tid >> 1;          // 0..127
    int lcol4 = (tid & 1) * 4;     // 0 or 4

    const float* Arow = X + (size_t)(rowBase + lrow) * D;
    const float* Brow = X + (size_t)(colBase + lrow) * D;

    int tx = tid & 15;   // 0..15 -> cols tx*8..
    int ty = tid >> 4;   // 0..15 -> rows ty*8..

    float acc[8][8];
#pragma unroll
    for (int i = 0; i < 8; ++i)
#pragma unroll
        for (int j = 0; j < 8; ++j) acc[i][j] = 0.f;

    for (int k0 = 0; k0 < D; k0 += BKK) {
        float4 a = *reinterpret_cast<const float4*>(Arow + k0 + lcol4);
        float4 b = *reinterpret_cast<const float4*>(Brow + k0 + lcol4);
        __syncthreads();
        As[lcol4 + 0][lrow] = a.x; As[lcol4 + 1][lrow] = a.y;
        As[lcol4 + 2][lrow] = a.z; As[lcol4 + 3][lrow] = a.w;
        Bs[lcol4 + 0][lrow] = b.x; Bs[lcol4 + 1][lrow] = b.y;
        Bs[lcol4 + 2][lrow] = b.z; Bs[lcol4 + 3][lrow] = b.w;
        __syncthreads();
#pragma unroll
        for (int kk = 0; kk < BKK; ++kk) {
            float4 a0 = *reinterpret_cast<const float4*>(&As[kk][ty * 8]);
            float4 a1 = *reinterpret_cast<const float4*>(&As[kk][ty * 8 + 4]);
            float4 b0 = *reinterpret_cast<const float4*>(&Bs[kk][tx * 8]);
            float4 b1 = *reinterpret_cast<const float4*>(&Bs[kk][tx * 8 + 4]);
            float av[8] = {a0.x, a0.y, a0.z, a0.w, a1.x, a1.y, a1.z, a1.w};
            float bv[8] = {b0.x, b0.y, b0.z, b0.w, b1.x, b1.y, b1.z, b1.w};
#pragma unroll
            for (int i = 0; i < 8; ++i)
#pragma unroll
                for (int j = 0; j < 8; ++j) acc[i][j] += av[i] * bv[j];
        }
    }

#pragma unroll
    for (int i = 0; i < 8; ++i) {
        int gi = rowBase + ty * 8 + i;
        float sqi = sq[gi];
        float* drow = dist + (size_t)gi * N + colBase;
#pragma unroll
        for (int j = 0; j < 8; ++j) {
            int gj = colBase + tx * 8 + j;
            float v = sqi + sq[gj] - 2.0f * acc[i][j];
            drow[tx * 8 + j] = sqrtf(fmaxf(v, 1e-12f));
        }
    }
}

// ---------------------------------------------------------------------------
// Kernel 3: per-row selection + masked logit sums
// ---------------------------------------------------------------------------
__device__ inline float blockReduceSumF(float v, float* s) {
    for (int off = 32; off; off >>= 1) v += __shfl_down(v, off);
    int tid = threadIdx.x, wid = tid >> 6;
    if ((tid & 63) == 0) s[wid] = v;
    __syncthreads();
    float r;
    if (tid == 0) { r = s[0] + s[1] + s[2] + s[3]; s[0] = r; }
    __syncthreads();
    r = s[0];
    __syncthreads();
    return r;
}

__device__ inline int blockReduceMinI(int v, int* s) {
    for (int off = 32; off; off >>= 1) v = min(v, __shfl_down(v, off));
    int tid = threadIdx.x, wid = tid >> 6;
    if ((tid & 63) == 0) s[wid] = v;
    __syncthreads();
    int r;
    if (tid == 0) { r = min(min(s[0], s[1]), min(s[2], s[3])); s[0] = r; }
    __syncthreads();
    r = s[0];
    __syncthreads();
    return r;
}

__device__ inline int blockReduceMaxI(int v, int* s) {
    for (int off = 32; off; off >>= 1) v = max(v, __shfl_down(v, off));
    int tid = threadIdx.x, wid = tid >> 6;
    if ((tid & 63) == 0) s[wid] = v;
    __syncthreads();
    int r;
    if (tid == 0) { r = max(max(s[0], s[1]), max(s[2], s[3])); s[0] = r; }
    __syncthreads();
    r = s[0];
    __syncthreads();
    return r;
}

#define NMAX 4096
__global__ __launch_bounds__(256) void rowselect_kernel(const float* __restrict__ dist,
                                                        const int* __restrict__ targets,
                                                        float* __restrict__ accum, int N) {
    __shared__ float rowL[NMAX];
    __shared__ float rowC[NMAX];
    __shared__ float sVal[4];
    __shared__ int   sIdx[4];
    __shared__ float sF[4];
    __shared__ int   sI[4];
    __shared__ float sMinVal;
    __shared__ int   sMinIdx;

    int row = blockIdx.x;
    int tid = threadIdx.x;
    const float* drow = dist + (size_t)row * N;

    for (int j = tid; j < N; j += 256) {
        float v = drow[j];
        rowL[j] = v;
        rowC[j] = (j == row) ? BIGV : v;
    }
    __syncthreads();

    // ---- extract (KSEL+1) smallest; thr = last extracted value ----
    float thr = BIGV;
    for (int it = 0; it <= KSEL; ++it) {
        float lv = BIGV;
        int li = -1;
        for (int j = tid; j < N; j += 256) {
            float v = rowC[j];
            if (v < lv) { lv = v; li = j; }
        }
        // block argmin
        for (int off = 32; off; off >>= 1) {
            float v2 = __shfl_down(lv, off);
            int i2 = __shfl_down(li, off);
            if (v2 < lv) { lv = v2; li = i2; }
        }
        int wid = tid >> 6;
        if ((tid & 63) == 0) { sVal[wid] = lv; sIdx[wid] = li; }
        __syncthreads();
        if (tid == 0) {
            float bv = sVal[0]; int bi = sIdx[0];
            for (int w = 1; w < 4; ++w)
                if (sVal[w] < bv) { bv = sVal[w]; bi = sIdx[w]; }
            sMinVal = bv; sMinIdx = bi;
            if (bi >= 0) rowC[bi] = BIGV;
        }
        __syncthreads();
        thr = sMinVal;
    }

    // ---- masked sums ----
    int ti = targets[row];
    float posS = 0.f, negS = 0.f;
    int firstPos = INT_MAX, anyNeg = 0, anyPosBelow = 0;
    for (int j = tid; j < N; j += 256) {
        if (j == row) continue;
        float d = rowL[j];
        bool same = (targets[j] == ti);
        if (same) { if (j < firstPos) firstPos = j; }
        else anyNeg = 1;
        if (d < thr) {
            float e = expf(ALPHA * (1.0f - d));
            if (same) { posS += e; anyPosBelow = 1; }
            else negS += e;
        }
    }
    posS = blockReduceSumF(posS, sF);
    negS = blockReduceSumF(negS, sF);
    firstPos = blockReduceMinI(firstPos, sI);
    anyNeg = blockReduceMaxI(anyNeg, sI);
    anyPosBelow = blockReduceMaxI(anyPosBelow, sI);

    if (tid == 0) {
        bool anyPos = (firstPos != INT_MAX);
        bool valid = anyPos && (anyNeg != 0);
        if (valid) {
            float posLogit = anyPosBelow ? posS
                                         : expf(ALPHA * (1.0f - rowL[firstPos]));
            float loss_i = -logf(posLogit / (posLogit + negS));
            atomicAdd(accum + 0, loss_i);
            atomicAdd(accum + 1, 1.0f);
            if (loss_i < 0.6f) atomicAdd(accum + 2, 1.0f);
        }
    }
}

// ---------------------------------------------------------------------------
// Kernel 4: finalize scalars
// ---------------------------------------------------------------------------
__global__ void finalize_kernel(const float* __restrict__ accum,
                                float* __restrict__ out, float n) {
    if (threadIdx.x == 0 && blockIdx.x == 0) {
        float nv = accum[1];
        out[0] = (nv > 0.f) ? accum[0] / nv : 0.f;
        out[1] = accum[2] / n;
        out[2] = 0.f;
        out[3] = 0.f;
    }
}

// ---------------------------------------------------------------------------
extern "C" void kernel_launch(void* const* d_in, const int* in_sizes, int n_in,
                              void* d_out, int out_size, void* d_ws, size_t ws_size,
                              hipStream_t stream) {
    const float* X = (const float*)d_in[0];
    const int* targets = (const int*)d_in[1];
    float* out = (float*)d_out;

    int N = in_sizes[1];              // 4096
    int D = in_sizes[0] / N;          // 1024

    float* dist = (float*)d_ws;                    // N*N floats
    float* sq   = dist + (size_t)N * N;            // N floats
    float* accum = sq + N;                         // 3 floats

    hipMemsetAsync(accum, 0, 3 * sizeof(float), stream);

    sqnorm_kernel<<<N, 256, 0, stream>>>(X, sq, D);

    dim3 grid(N / BN, N / BM);
    distgemm_kernel<<<grid, 256, 0, stream>>>(X, sq, dist, N, D);

    rowselect_kernel<<<N, 256, 0, stream>>>(dist, targets, accum, N);

    finalize_kernel<<<1, 64, 0, stream>>>(accum, out, (float)N);
}

// Round 2
// 249.903 us; speedup vs baseline: 2.4262x; 2.4262x over previous
//
#include <hip/hip_runtime.h>
#include <hip/hip_bf16.h>
#include <cfloat>
#include <climits>
#include <cstdint>

#define ALPHA 30.0f
#define KSEL 16          // threshold = sorted[:,16] (17th smallest off-diag)
#define BIGV 1e30f

typedef __attribute__((ext_vector_type(8))) short bf16x8;
typedef __attribute__((ext_vector_type(4))) float f32x4;

#define LDS_PTR(p) ((__attribute__((address_space(3))) uint32_t*)(p))
#define GLB_PTR(p) ((const __attribute__((address_space(1))) uint32_t*)(p))

// ---------------------------------------------------------------------------
// Kernel 0: fp32 -> bf16 (RNE) conversion, 4 elems/thread
// ---------------------------------------------------------------------------
__global__ __launch_bounds__(256) void cvt_kernel(const float* __restrict__ X,
                                                  ushort* __restrict__ Xb, int n4) {
    int i = blockIdx.x * 256 + threadIdx.x;
    if (i < n4) {
        float4 v = *reinterpret_cast<const float4*>(X + (size_t)i * 4);
        ushort4 o;
        uint32_t b;
        b = __builtin_bit_cast(uint32_t, v.x); o.x = (ushort)((b + 0x7FFF + ((b >> 16) & 1)) >> 16);
        b = __builtin_bit_cast(uint32_t, v.y); o.y = (ushort)((b + 0x7FFF + ((b >> 16) & 1)) >> 16);
        b = __builtin_bit_cast(uint32_t, v.z); o.z = (ushort)((b + 0x7FFF + ((b >> 16) & 1)) >> 16);
        b = __builtin_bit_cast(uint32_t, v.w); o.w = (ushort)((b + 0x7FFF + ((b >> 16) & 1)) >> 16);
        *reinterpret_cast<ushort4*>(Xb + (size_t)i * 4) = o;
    }
}

// ---------------------------------------------------------------------------
// Kernel 1: per-row squared norms (fp32, exact as reference)
// ---------------------------------------------------------------------------
__global__ __launch_bounds__(256) void sqnorm_kernel(const float* __restrict__ X,
                                                     float* __restrict__ sq, int D) {
    int row = blockIdx.x;
    const float4* xr = reinterpret_cast<const float4*>(X + (size_t)row * D);
    float s = 0.f;
    for (int c = threadIdx.x; c < D / 4; c += blockDim.x) {
        float4 v = xr[c];
        s += v.x * v.x + v.y * v.y + v.z * v.z + v.w * v.w;
    }
    __shared__ float sw[4];
    for (int off = 32; off; off >>= 1) s += __shfl_down(s, off);
    int tid = threadIdx.x, wid = tid >> 6;
    if ((tid & 63) == 0) sw[wid] = s;
    __syncthreads();
    if (tid == 0) sq[row] = sw[0] + sw[1] + sw[2] + sw[3];
}

// ---------------------------------------------------------------------------
// Kernel 2: bf16 MFMA dist-GEMM (m97-style 128x128 tile, BK=32, 4 waves 2x2)
// dist[i][j] = sqrt(max(sq_i + sq_j - 2*dot_bf16(x_i, x_j), 1e-12))
// C = X Xᵀ is symmetric, so any C/D row<->col transpose is harmless.
// ---------------------------------------------------------------------------
#define GBM 128
#define GBK 32
__global__ __launch_bounds__(256) void distgemm_mfma(const ushort* __restrict__ Xb,
                                                     const float* __restrict__ sq,
                                                     float* __restrict__ dist,
                                                     int N, int D) {
    __shared__ ushort As[GBM * GBK];   // [row][k], 8 KB, linear (global_load_lds dest)
    __shared__ ushort Bs[GBM * GBK];

    int tid = threadIdx.x;
    int lane = tid & 63;
    int wave = tid >> 6;       // 0..3
    int waveR = wave >> 1;     // 0..1
    int waveC = wave & 1;      // 0..1

    int rowBase = blockIdx.y * GBM;
    int colBase = blockIdx.x * GBM;

    f32x4 acc[4][4];
#pragma unroll
    for (int m = 0; m < 4; ++m)
#pragma unroll
        for (int n2 = 0; n2 < 4; ++n2) {
            f32x4 z = {0.f, 0.f, 0.f, 0.f};
            acc[m][n2] = z;
        }

    for (int k0 = 0; k0 < D; k0 += GBK) {
        // stage 8KB A-tile + 8KB B-tile: 8 wave-calls each of 1KB (64 lanes x 16B)
#pragma unroll
        for (int p = 0; p < 2; ++p) {
            int c = wave + 4 * p;                 // 0..7
            int byteoff = c * 1024 + lane * 16;   // within tile
            int r  = byteoff >> 6;                // row (64B per row)
            int kk = (byteoff & 63) >> 1;         // bf16 index within row
            const ushort* gA = Xb + (size_t)(rowBase + r) * D + k0 + kk;
            const ushort* gB = Xb + (size_t)(colBase + r) * D + k0 + kk;
            __builtin_amdgcn_global_load_lds(GLB_PTR(gA), LDS_PTR(As + c * 512), 16, 0, 0);
            __builtin_amdgcn_global_load_lds(GLB_PTR(gB), LDS_PTR(Bs + c * 512), 16, 0, 0);
        }
        __syncthreads();   // drains vmcnt(0): staged tile visible to all waves

        bf16x8 aF[4], bF[4];
        int chunk = (lane >> 4) * 8;   // k sub-chunk of 8 bf16
#pragma unroll
        for (int m = 0; m < 4; ++m) {
            int rl = waveR * 64 + m * 16 + (lane & 15);
            aF[m] = *reinterpret_cast<const bf16x8*>(&As[rl * GBK + chunk]);
        }
#pragma unroll
        for (int n2 = 0; n2 < 4; ++n2) {
            int rl = waveC * 64 + n2 * 16 + (lane & 15);
            bF[n2] = *reinterpret_cast<const bf16x8*>(&Bs[rl * GBK + chunk]);
        }
#pragma unroll
        for (int m = 0; m < 4; ++m)
#pragma unroll
            for (int n2 = 0; n2 < 4; ++n2)
                acc[m][n2] = __builtin_amdgcn_mfma_f32_16x16x32_bf16(aF[m], bF[n2], acc[m][n2], 0, 0, 0);
        __syncthreads();   // all waves done reading before next stage overwrites
    }

    // epilogue: C/D map col=lane&15, row=(lane>>4)*4+reg
    int cr = (lane >> 4) * 4;
    int cc = lane & 15;
#pragma unroll
    for (int m = 0; m < 4; ++m) {
#pragma unroll
        for (int n2 = 0; n2 < 4; ++n2) {
            int gcol = colBase + waveC * 64 + n2 * 16 + cc;
            float sqc = sq[gcol];
#pragma unroll
            for (int r = 0; r < 4; ++r) {
                int grow = rowBase + waveR * 64 + m * 16 + cr + r;
                float v = sq[grow] + sqc - 2.0f * acc[m][n2][r];
                dist[(size_t)grow * N + gcol] = sqrtf(fmaxf(v, 1e-12f));
            }
        }
    }
}

// ---------------------------------------------------------------------------
// block reduce helpers (256 threads, 4 waves)
// ---------------------------------------------------------------------------
__device__ inline float blockReduceSumF(float v, float* s) {
    for (int off = 32; off; off >>= 1) v += __shfl_down(v, off);
    int tid = threadIdx.x, wid = tid >> 6;
    if ((tid & 63) == 0) s[wid] = v;
    __syncthreads();
    float r;
    if (tid == 0) { r = s[0] + s[1] + s[2] + s[3]; s[0] = r; }
    __syncthreads();
    r = s[0];
    __syncthreads();
    return r;
}

__device__ inline int blockReduceMinI(int v, int* s) {
    for (int off = 32; off; off >>= 1) v = min(v, __shfl_down(v, off));
    int tid = threadIdx.x, wid = tid >> 6;
    if ((tid & 63) == 0) s[wid] = v;
    __syncthreads();
    int r;
    if (tid == 0) { r = min(min(s[0], s[1]), min(s[2], s[3])); s[0] = r; }
    __syncthreads();
    r = s[0];
    __syncthreads();
    return r;
}

__device__ inline int blockReduceMaxI(int v, int* s) {
    for (int off = 32; off; off >>= 1) v = max(v, __shfl_down(v, off));
    int tid = threadIdx.x, wid = tid >> 6;
    if ((tid & 63) == 0) s[wid] = v;
    __syncthreads();
    int r;
    if (tid == 0) { r = max(max(s[0], s[1]), max(s[2], s[3])); s[0] = r; }
    __syncthreads();
    r = s[0];
    __syncthreads();
    return r;
}

// ---------------------------------------------------------------------------
// Kernel 3: per-row threshold via histogram + masked logit sums
// ---------------------------------------------------------------------------
#define NMAX 4096
#define NBIN 1024
#define CANDCAP 1024
__global__ __launch_bounds__(256) void rowselect_kernel(const float* __restrict__ dist,
                                                        const int* __restrict__ targets,
                                                        float* __restrict__ accum, int N) {
    __shared__ float rowD[NMAX];
    __shared__ int hist[NBIN];
    __shared__ int chunkS[256];
    __shared__ float cand[CANDCAP];
    __shared__ int candIdx[CANDCAP];
    __shared__ float sF[4];
    __shared__ int sI[4];
    __shared__ int s_b1, s_c1, s_cnt;
    __shared__ float s_thr;

    int row = blockIdx.x;
    int tid = threadIdx.x;
    const float* drow = dist + (size_t)row * N;

    // load row; diagonal -> BIG (excluded from order statistic)
    for (int j = tid; j < N; j += 256)
        rowD[j] = (j == row) ? BIGV : drow[j];
#pragma unroll
    for (int q = 0; q < NBIN / 256; ++q) hist[tid + q * 256] = 0;
    if (tid == 0) s_cnt = 0;
    __syncthreads();

    // pass 1: histogram, bins over [0,2), width 1/512
    for (int j = tid; j < N; j += 256) {
        int bin = min(max((int)(rowD[j] * 512.f), 0), NBIN - 1);
        atomicAdd(&hist[bin], 1);
    }
    __syncthreads();

    // find bin b1 where cumulative count crosses KSEL+1 = 17
    {
        int cs = 0;
#pragma unroll
        for (int q = 0; q < 4; ++q) cs += hist[tid * 4 + q];
        chunkS[tid] = cs;
    }
    __syncthreads();
    if (tid == 0) {
        int cum = 0, b1 = NBIN - 1, c1 = 0;
        for (int c = 0; c < 256; ++c) {
            if (cum + chunkS[c] >= KSEL + 1) {
                int cc = cum;
                for (int q = 0; q < 4; ++q) {
                    int h = hist[c * 4 + q];
                    if (cc + h >= KSEL + 1) { b1 = c * 4 + q; c1 = cc; break; }
                    cc += h;
                }
                break;
            }
            cum += chunkS[c];
        }
        s_b1 = b1; s_c1 = c1;
    }
    __syncthreads();

    // pass 2: collect elements in crossing bin
    int b1 = s_b1;
    for (int j = tid; j < N; j += 256) {
        float v = rowD[j];
        int bin = min(max((int)(v * 512.f), 0), NBIN - 1);
        if (bin == b1) {
            int p = atomicAdd(&s_cnt, 1);
            if (p < CANDCAP) { cand[p] = v; candIdx[p] = j; }
        }
    }
    __syncthreads();

    // exact rank within bin (tie-break by index)
    int cnt = min(s_cnt, CANDCAP);
    int r1 = KSEL - s_c1;   // 0-based rank within bin
    for (int e = tid; e < cnt; e += 256) {
        float v = cand[e]; int id = candIdx[e];
        int r = 0;
        for (int q = 0; q < cnt; ++q) {
            float u = cand[q];
            if (u < v || (u == v && candIdx[q] < id)) ++r;
        }
        if (r == r1) s_thr = v;
    }
    __syncthreads();
    float thr = s_thr;

    // pass 3: masked sums
    int ti = targets[row];
    float posS = 0.f, negS = 0.f;
    int firstPos = INT_MAX, anyNeg = 0, anyPosBelow = 0;
    for (int j = tid; j < N; j += 256) {
        if (j == row) continue;
        float d = rowD[j];
        bool same = (targets[j] == ti);
        if (same) { if (j < firstPos) firstPos = j; }
        else anyNeg = 1;
        if (d < thr) {
            float e = expf(ALPHA * (1.0f - d));
            if (same) { posS += e; anyPosBelow = 1; }
            else negS += e;
        }
    }
    posS = blockReduceSumF(posS, sF);
    negS = blockReduceSumF(negS, sF);
    firstPos = blockReduceMinI(firstPos, sI);
    anyNeg = blockReduceMaxI(anyNeg, sI);
    anyPosBelow = blockReduceMaxI(anyPosBelow, sI);

    if (tid == 0) {
        bool anyPos = (firstPos != INT_MAX);
        bool valid = anyPos && (anyNeg != 0);
        if (valid) {
            float posLogit = anyPosBelow ? posS
                                         : expf(ALPHA * (1.0f - rowD[firstPos]));
            float loss_i = -logf(posLogit / (posLogit + negS));
            atomicAdd(accum + 0, loss_i);
            atomicAdd(accum + 1, 1.0f);
            if (loss_i < 0.6f) atomicAdd(accum + 2, 1.0f);
        }
    }
}

// ---------------------------------------------------------------------------
// Kernel 4: finalize scalars
// ---------------------------------------------------------------------------
__global__ void finalize_kernel(const float* __restrict__ accum,
                                float* __restrict__ out, float n) {
    if (threadIdx.x == 0 && blockIdx.x == 0) {
        float nv = accum[1];
        out[0] = (nv > 0.f) ? accum[0] / nv : 0.f;
        out[1] = accum[2] / n;
        out[2] = 0.f;
        out[3] = 0.f;
    }
}

// ---------------------------------------------------------------------------
extern "C" void kernel_launch(void* const* d_in, const int* in_sizes, int n_in,
                              void* d_out, int out_size, void* d_ws, size_t ws_size,
                              hipStream_t stream) {
    const float* X = (const float*)d_in[0];
    const int* targets = (const int*)d_in[1];
    float* out = (float*)d_out;

    int N = in_sizes[1];             // 4096
    int D = in_sizes[0] / N;         // 1024

    float* dist  = (float*)d_ws;                      // N*N f32
    float* sq    = dist + (size_t)N * N;              // N f32
    float* accum = sq + N;                            // 8 f32 (padded)
    ushort* Xb   = (ushort*)(accum + 8);              // N*D bf16

    hipMemsetAsync(accum, 0, 8 * sizeof(float), stream);

    int n4 = (N * D) / 4;
    cvt_kernel<<<(n4 + 255) / 256, 256, 0, stream>>>(X, Xb, n4);
    sqnorm_kernel<<<N, 256, 0, stream>>>(X, sq, D);

    dim3 grid(N / GBM, N / GBM);
    distgemm_mfma<<<grid, 256, 0, stream>>>(Xb, sq, dist, N, D);

    rowselect_kernel<<<N, 256, 0, stream>>>(dist, targets, accum, N);

    finalize_kernel<<<1, 64, 0, stream>>>(accum, out, (float)N);
}